// Round 5
// baseline (13.655 us; speedup 1.0000x reference)
//
#include <hip/hip_runtime.h>

// BagOfWords: out[b][v] = count of token v in docs[b][:] / SEQ
// docs: int32 [256, 2048], out: float32 [256, 32000]
//
// R5 = R4 structure (4 vocab chunks x 512 threads, 4 blocks/CU, 32 waves/CU)
//  + XCD swizzle: the 4 chunk-blocks of a row get ids congruent mod 8 ->
//    same XCD L2 -> row fetched from HBM once per XCD, not 4x.
//  + u16-packed LDS bins (counts <= 2048 < 65536, exact): halves LDS
//    zero/readback traffic. 16 KB LDS per block.
//  + token loads hoisted above the zero phase (latency hides under zeroing).

#define VOCAB 32000
#define BATCH 256
#define SEQ   2048
#define NCHUNK 4
#define CHUNK (VOCAB / NCHUNK)   // 8000 bins -> 4000 packed u32 = 16 KB LDS
#define BLK   512

__global__ __launch_bounds__(BLK) void bow_hist_kernel(
    const int* __restrict__ docs, float* __restrict__ out) {
    __shared__ unsigned int binsP[CHUNK / 2];   // 2 u16 counters per u32

    // Decode the XCD-friendly id: id = (b&7) | ((c + 4*(b>>3)) << 3)
    // => b = (id>>5)*8 + (id&7), c = (id>>3)&3. Bijective on [0,1024).
    // Consecutive ids round-robin XCDs, so ids equal mod 8 share an XCD:
    // all 4 chunks of row b have id % 8 == b % 8 -> one HBM fetch of the
    // row per XCD, 3 L2 hits.
    const int id   = blockIdx.x;
    const int b    = ((id >> 5) << 3) + (id & 7);
    const int c    = (id >> 3) & 3;
    const int base = c * CHUNK;
    const int tid  = threadIdx.x;

    // Hoist the row load: 512 int4 covers all 2048 tokens (1 per thread);
    // global-load latency hides under the LDS zeroing below.
    const int4* row4 = reinterpret_cast<const int4*>(docs + (size_t)b * SEQ);
    int4 t = row4[tid];

    // 1) zero the packed histogram (1000 uint4 -> 2 iters/thread)
    uint4* binsP4 = reinterpret_cast<uint4*>(binsP);
    for (int i = tid; i < CHUNK / 8; i += BLK) {
        binsP4[i] = make_uint4(0u, 0u, 0u, 0u);
    }
    __syncthreads();

    // 2) scatter with packed u16 atomics: bin r lives in word r>>1,
    //    half selected by r&1. Counts <= 2048 so no carry into the
    //    neighbor's halfword.
    int r;
    r = t.x - base;
    if ((unsigned)r < (unsigned)CHUNK)
        atomicAdd(&binsP[r >> 1], (r & 1) ? 0x10000u : 1u);
    r = t.y - base;
    if ((unsigned)r < (unsigned)CHUNK)
        atomicAdd(&binsP[r >> 1], (r & 1) ? 0x10000u : 1u);
    r = t.z - base;
    if ((unsigned)r < (unsigned)CHUNK)
        atomicAdd(&binsP[r >> 1], (r & 1) ? 0x10000u : 1u);
    r = t.w - base;
    if ((unsigned)r < (unsigned)CHUNK)
        atomicAdd(&binsP[r >> 1], (r & 1) ? 0x10000u : 1u);
    __syncthreads();

    // 3) stream out, normalized. Each uint4 holds 8 bins -> 8 floats ->
    //    two float4 stores (back-to-back, full-line coverage in L2).
    float* orow = out + (size_t)b * VOCAB + base;
    const float inv = 1.0f / (float)SEQ;   // exact power of two
    for (int i = tid; i < CHUNK / 8; i += BLK) {   // 2 iters/thread
        uint4 u = binsP4[i];
        float4 v0, v1;
        v0.x = (float)(u.x & 0xFFFFu) * inv;
        v0.y = (float)(u.x >> 16)     * inv;
        v0.z = (float)(u.y & 0xFFFFu) * inv;
        v0.w = (float)(u.y >> 16)     * inv;
        v1.x = (float)(u.z & 0xFFFFu) * inv;
        v1.y = (float)(u.z >> 16)     * inv;
        v1.z = (float)(u.w & 0xFFFFu) * inv;
        v1.w = (float)(u.w >> 16)     * inv;
        reinterpret_cast<float4*>(orow)[i * 2 + 0] = v0;
        reinterpret_cast<float4*>(orow)[i * 2 + 1] = v1;
    }
}

extern "C" void kernel_launch(void* const* d_in, const int* in_sizes, int n_in,
                              void* d_out, int out_size, void* d_ws, size_t ws_size,
                              hipStream_t stream) {
    const int* docs = (const int*)d_in[0];
    float* out = (float*)d_out;
    bow_hist_kernel<<<dim3(BATCH * NCHUNK), dim3(BLK), 0, stream>>>(docs, out);
}